// Round 11
// baseline (145.761 us; speedup 1.0000x reference)
//
#include <hip/hip_runtime.h>

#define NN 50000
#define NE 800000
#define NBUCK 196        // coarse buckets: dst>>8
#define BCAP 5120
#define NPART 256
#define EPP (NE / NPART) // 3125

typedef short short8 __attribute__((ext_vector_type(8)));
typedef float f32x4 __attribute__((ext_vector_type(4)));
union U4 { uint4 u; short8 h; };

// ---------------- bf16 helpers (RNE) ----------------
__device__ __forceinline__ unsigned f2bf(float f) {
  union { float f; unsigned u; } v; v.f = f;
  return (v.u + 0x7FFFu + ((v.u >> 16) & 1u)) >> 16;
}
__device__ __forceinline__ float2 upk(unsigned u) {
  union { unsigned u; float f; } a, b;
  a.u = u << 16; b.u = u & 0xFFFF0000u;
  return make_float2(a.f, b.f);
}
__device__ __forceinline__ float bf2f(unsigned short b) {
  union { unsigned u; float f; } v; v.u = ((unsigned)b) << 16;
  return v.f;
}
__device__ __forceinline__ unsigned pk2(float a, float b) {
  return f2bf(a) | (f2bf(b) << 16);
}

// ---------------- prep: W1T/W2T bf16 transposed+swizzled; also zeros gcur ----------------
__global__ __launch_bounds__(256) void k_prep(const float* __restrict__ W1,
                                              const float* __restrict__ W2,
                                              unsigned short* __restrict__ W1T,
                                              unsigned short* __restrict__ W2T,
                                              unsigned* __restrict__ gcur) {
  int b = blockIdx.x, t = threadIdx.x;
  if (b == 0 && t < NBUCK) gcur[t] = 0;
  {
    int idx = b * 256 + t;
    int k = idx >> 7, n = idx & 127;
    W1T[(n << 7) + (k ^ ((n & 7) << 3))] = (unsigned short)f2bf(W1[idx]);
  }
  {
    if (t < 128) {
      int idx = b * 128 + t;
      int k = idx >> 6, n = idx & 63;
      W2T[(n << 7) + (k ^ ((n & 7) << 3))] = (unsigned short)f2bf(W2[idx]);
    }
  }
}

// ---------------- Phase A partition (blocks 0..255) + MFMA GEMM-1 (blocks 256..) ----------------
__global__ __launch_bounds__(256) void k_partmm1(const int* __restrict__ src,
                                                 const int* __restrict__ dst,
                                                 unsigned* __restrict__ gcur,
                                                 unsigned* __restrict__ part,
                                                 const float* __restrict__ X,
                                                 const unsigned short* __restrict__ W1T,
                                                 unsigned* __restrict__ Hbu) {
  __shared__ __attribute__((aligned(16))) unsigned smem[12288];  // 48 KB
  __shared__ int wsum[4];
  const int tid = threadIdx.x;
  if (blockIdx.x < NPART) {
    // ---- partition role ----
    unsigned* stage = smem;
    unsigned* hist  = smem + 3200;
    unsigned* curs  = smem + 3400;
    unsigned* bbs   = smem + 3600;
    const int e0 = blockIdx.x * EPP;
    for (int i = tid; i < NBUCK; i += 256) hist[i] = 0;
    __syncthreads();
    for (int k = tid; k < EPP; k += 256)
      atomicAdd(&hist[((unsigned)dst[e0 + k]) >> 8], 1u);
    __syncthreads();
    {
      int lane = tid & 63, w = tid >> 6;
      unsigned v = (tid < NBUCK) ? hist[tid] : 0;
      unsigned incl = v;
#pragma unroll
      for (int d = 1; d < 64; d <<= 1) {
        unsigned u = __shfl_up(incl, d);
        if (lane >= d) incl += u;
      }
      if (lane == 63) wsum[w] = (int)incl;
      __syncthreads();
      unsigned wpre = 0;
      for (int j = 0; j < w; ++j) wpre += (unsigned)wsum[j];
      if (tid < NBUCK) curs[tid] = wpre + incl - v;
    }
    __syncthreads();
    for (int k = tid; k < EPP; k += 256) {
      int d = dst[e0 + k];
      unsigned slot = atomicAdd(&curs[((unsigned)d) >> 8], 1u);
      stage[slot] = (((unsigned)src[e0 + k]) << 16) | (unsigned)d;
    }
    __syncthreads();
    if (tid < NBUCK) bbs[tid] = atomicAdd(&gcur[tid], hist[tid]);
    __syncthreads();
    for (int k = tid; k < EPP; k += 256) {
      unsigned v = stage[k];
      unsigned b = (v & 0xFFFFu) >> 8;
      unsigned startb = curs[b] - hist[b];
      part[b * BCAP + bbs[b] + ((unsigned)k - startb)] = v;
    }
  } else {
    // ---- MFMA GEMM-1: 64 rows x 128 cols per block ----
    uint4* w1t4 = (uint4*)smem;
    uint4* xs4  = (uint4*)(smem + 8192);
    const int base = (blockIdx.x - NPART) * 64;
    const uint4* W1Tg = (const uint4*)W1T;
    const float4* X4 = (const float4*)X;
#pragma unroll
    for (int it = 0; it < 8; ++it) w1t4[tid + 256 * it] = W1Tg[tid + 256 * it];
#pragma unroll
    for (int it = 0; it < 4; ++it) {
      int j = tid + 256 * it;
      int row = j >> 4, c16 = j & 15;
      int grow = base + row;
      uint4 v = make_uint4(0, 0, 0, 0);
      if (grow < NN) {
        float4 f0 = X4[(size_t)grow * 32 + c16 * 2];
        float4 f1 = X4[(size_t)grow * 32 + c16 * 2 + 1];
        v = make_uint4(pk2(f0.x, f0.y), pk2(f0.z, f0.w), pk2(f1.x, f1.y), pk2(f1.z, f1.w));
      }
      xs4[row * 16 + (c16 ^ (row & 7))] = v;
    }
    __syncthreads();
    const int lane = tid & 63, wv = tid >> 6;
    const int l7 = lane & 7, lg = lane >> 4;
    f32x4 acc[8];
#pragma unroll
    for (int c = 0; c < 8; ++c) acc[c] = (f32x4){0.f, 0.f, 0.f, 0.f};
    const int arow = wv * 16 + (lane & 15);
#pragma unroll
    for (int kk = 0; kk < 4; ++kk) {
      int kcc = kk * 4 + lg;
      U4 a; a.u = xs4[arow * 16 + (kcc ^ l7)];
#pragma unroll
      for (int c = 0; c < 8; ++c) {
        int n = c * 16 + (lane & 15);
        U4 b; b.u = w1t4[n * 16 + (kcc ^ l7)];
        acc[c] = __builtin_amdgcn_mfma_f32_16x16x32_bf16(a.h, b.h, acc[c], 0, 0, 0);
      }
    }
#pragma unroll
    for (int c = 0; c < 8; ++c) {
#pragma unroll
      for (int r = 0; r < 4; ++r) {
        int grow = base + wv * 16 + lg * 4 + r;
        unsigned mb = f2bf(acc[c][r]);
        unsigned ob = (unsigned)__shfl_xor((int)mb, 1);
        if (((lane & 1) == 0) && grow < NN)
          Hbu[(size_t)grow * 64 + c * 8 + ((lane & 15) >> 1)] = mb | (ob << 16);
      }
    }
  }
}

// ---------------- Phase B: per-bucket bin sort + fused base-scan + Hb prescale ----------------
__global__ __launch_bounds__(256) void k_bucket(const unsigned* __restrict__ gcur,
                                                const unsigned* __restrict__ part,
                                                int* __restrict__ off,
                                                float* __restrict__ dinv,
                                                unsigned short* __restrict__ ssrc,
                                                unsigned* __restrict__ Hb) {
  __shared__ unsigned hist[256], curs[256], sb[256];
  __shared__ float dvs[256];
  __shared__ unsigned short ssr[BCAP];
  __shared__ int wsum[4];
  const int tid = threadIdx.x, b = blockIdx.x;
  const int lane = tid & 63, w = tid >> 6;
  // fused bucket-base scan (was k_bksc): exclusive scan of gcur into sb
  {
    unsigned g = (tid < NBUCK) ? gcur[tid] : 0;
    unsigned incl = g;
#pragma unroll
    for (int d = 1; d < 64; d <<= 1) {
      unsigned u = __shfl_up(incl, d);
      if (lane >= d) incl += u;
    }
    if (lane == 63) wsum[w] = (int)incl;
    __syncthreads();
    unsigned wpre = 0;
    for (int j = 0; j < w; ++j) wpre += (unsigned)wsum[j];
    sb[tid] = wpre + incl - g;
  }
  __syncthreads();
  const int nb = (int)gcur[b];
  const int base = (int)sb[b];
  const unsigned* pp = part + (size_t)b * BCAP;
  hist[tid] = 0;
  __syncthreads();
  for (int k = tid; k < nb; k += 256) atomicAdd(&hist[pp[k] & 255u], 1u);
  __syncthreads();
  unsigned v = hist[tid];
  unsigned incl = v;
#pragma unroll
  for (int d = 1; d < 64; d <<= 1) {
    unsigned u = __shfl_up(incl, d);
    if (lane >= d) incl += u;
  }
  if (lane == 63) wsum[w] = (int)incl;
  __syncthreads();
  unsigned wpre = 0;
  for (int j = 0; j < w; ++j) wpre += (unsigned)wsum[j];
  unsigned excl = wpre + incl - v;
  curs[tid] = excl;
  float dv = rsqrtf((float)(v + 1));
  dvs[tid] = dv;
  int node = b * 256 + tid;
  if (node < NN) {
    off[node] = base + (int)excl;
    dinv[node] = dv;
  } else if (node == NN) {
    off[NN] = base + (int)excl;
  }
  __syncthreads();
  for (int k = tid; k < nb; k += 256) {
    unsigned vv = pp[k];
    unsigned slot = atomicAdd(&curs[vv & 255u], 1u);
    ssr[slot] = (unsigned short)(vv >> 16);
  }
  __syncthreads();
  for (int k = tid; k < nb; k += 256) ssrc[base + k] = ssr[k];
  // ---- prescale Hb rows of this bucket: Hb[n] *= dinv[n] ----
  uint4* HbT = (uint4*)Hb + (size_t)b * 4096;  // 256 rows x 16 uint4
#pragma unroll
  for (int i = 0; i < 16; ++i) {
    int idx = tid + 256 * i;
    int row = idx >> 4;
    int grow = b * 256 + row;
    if (grow < NN) {
      uint4 u = HbT[idx];
      float s = dvs[row];
      float2 a0 = upk(u.x), a1 = upk(u.y), a2 = upk(u.z), a3 = upk(u.w);
      u.x = pk2(a0.x * s, a0.y * s);
      u.y = pk2(a1.x * s, a1.y * s);
      u.z = pk2(a2.x * s, a2.y * s);
      u.w = pk2(a3.x * s, a3.y * s);
      HbT[idx] = u;
    }
  }
}

// ---------------- agg1: acc = Hb'[n] + sum Hb'[s]; h2 = relu(dn*acc + b1) ----------------
__global__ __launch_bounds__(256) void k_agg1(const unsigned* __restrict__ Hb,
                                              const int* __restrict__ off,
                                              const unsigned short* __restrict__ ssrc,
                                              const float* __restrict__ dinv,
                                              const float* __restrict__ b1,
                                              unsigned* __restrict__ H2) {
  int n = (blockIdx.x * 256 + threadIdx.x) >> 6;
  int lane = threadIdx.x & 63;
  if (n >= NN) return;
  float dn = dinv[n];
  int jb = off[n], je = off[n + 1];
  float2 acc = upk(Hb[(size_t)n * 64 + lane]);  // self term (prescaled)
  int j = jb;
  int ja = (jb + 7) & ~7;
  if (ja > je) ja = je;
  for (; j < ja; ++j) {  // head to 16B alignment
    float2 f = upk(Hb[(size_t)ssrc[j] * 64 + lane]);
    acc.x += f.x; acc.y += f.y;
  }
  for (; j + 7 < je; j += 8) {
    uint4 sp = *(const uint4*)(ssrc + j);  // 8 src ids, one broadcast load
    unsigned s0 = sp.x & 0xFFFFu, s1 = sp.x >> 16;
    unsigned s2 = sp.y & 0xFFFFu, s3 = sp.y >> 16;
    unsigned s4 = sp.z & 0xFFFFu, s5 = sp.z >> 16;
    unsigned s6 = sp.w & 0xFFFFu, s7 = sp.w >> 16;
    unsigned u0 = Hb[(size_t)s0 * 64 + lane], u1 = Hb[(size_t)s1 * 64 + lane];
    unsigned u2 = Hb[(size_t)s2 * 64 + lane], u3 = Hb[(size_t)s3 * 64 + lane];
    unsigned u4 = Hb[(size_t)s4 * 64 + lane], u5 = Hb[(size_t)s5 * 64 + lane];
    unsigned u6 = Hb[(size_t)s6 * 64 + lane], u7 = Hb[(size_t)s7 * 64 + lane];
    float2 f0 = upk(u0), f1 = upk(u1), f2 = upk(u2), f3 = upk(u3);
    float2 f4 = upk(u4), f5 = upk(u5), f6 = upk(u6), f7 = upk(u7);
    acc.x += f0.x + f1.x + f2.x + f3.x + f4.x + f5.x + f6.x + f7.x;
    acc.y += f0.y + f1.y + f2.y + f3.y + f4.y + f5.y + f6.y + f7.y;
  }
  for (; j < je; ++j) {
    float2 f = upk(Hb[(size_t)ssrc[j] * 64 + lane]);
    acc.x += f.x; acc.y += f.y;
  }
  float2 b = ((const float2*)b1)[lane];
  float hx = fmaxf(fmaf(dn, acc.x, b.x), 0.f);
  float hy = fmaxf(fmaf(dn, acc.y, b.y), 0.f);
  H2[(size_t)n * 64 + lane] = pk2(hx, hy);
}

// ---------------- MFMA GEMM-2: 64 rows x 64 cols per block ----------------
__global__ __launch_bounds__(256) void k_mm2(const unsigned* __restrict__ H2,
                                             const unsigned short* __restrict__ W2T,
                                             const float* __restrict__ dinv,
                                             unsigned* __restrict__ H3u) {
  __shared__ __attribute__((aligned(16))) unsigned smem[8192];  // 32 KB
  uint4* w2t4 = (uint4*)smem;
  uint4* xs4  = (uint4*)(smem + 4096);
  const int tid = threadIdx.x;
  const int base = blockIdx.x * 64;
  const uint4* W2Tg = (const uint4*)W2T;
  const uint4* H2v = (const uint4*)H2;
#pragma unroll
  for (int it = 0; it < 4; ++it) w2t4[tid + 256 * it] = W2Tg[tid + 256 * it];
#pragma unroll
  for (int it = 0; it < 4; ++it) {
    int j = tid + 256 * it;
    int row = j >> 4, c16 = j & 15;
    int grow = base + row;
    uint4 v = (grow < NN) ? H2v[(size_t)grow * 16 + c16] : make_uint4(0, 0, 0, 0);
    xs4[row * 16 + (c16 ^ (row & 7))] = v;
  }
  __syncthreads();
  const int lane = tid & 63, wv = tid >> 6;
  const int l7 = lane & 7, lg = lane >> 4;
  f32x4 acc[4];
#pragma unroll
  for (int c = 0; c < 4; ++c) acc[c] = (f32x4){0.f, 0.f, 0.f, 0.f};
  const int arow = wv * 16 + (lane & 15);
#pragma unroll
  for (int kk = 0; kk < 4; ++kk) {
    int kcc = kk * 4 + lg;
    U4 a; a.u = xs4[arow * 16 + (kcc ^ l7)];
#pragma unroll
    for (int c = 0; c < 4; ++c) {
      int n = c * 16 + (lane & 15);
      U4 b; b.u = w2t4[n * 16 + (kcc ^ l7)];
      acc[c] = __builtin_amdgcn_mfma_f32_16x16x32_bf16(a.h, b.h, acc[c], 0, 0, 0);
    }
  }
#pragma unroll
  for (int c = 0; c < 4; ++c) {
#pragma unroll
    for (int r = 0; r < 4; ++r) {
      int grow = base + wv * 16 + lg * 4 + r;
      float dn = (grow < NN) ? dinv[grow] : 0.f;
      unsigned mb = f2bf(acc[c][r] * dn);
      unsigned ob = (unsigned)__shfl_xor((int)mb, 1);
      if (((lane & 1) == 0) && grow < NN)
        H3u[(size_t)grow * 32 + c * 8 + ((lane & 15) >> 1)] = mb | (ob << 16);
    }
  }
}

// ---------------- agg2: out = relu(dn*(H3'[n] + sum H3'[s]) + b2) ----------------
__global__ __launch_bounds__(256) void k_agg2(const unsigned short* __restrict__ H3,
                                              const int* __restrict__ off,
                                              const unsigned short* __restrict__ ssrc,
                                              const float* __restrict__ dinv,
                                              const float* __restrict__ b2,
                                              float* __restrict__ out) {
  int n = (blockIdx.x * 256 + threadIdx.x) >> 6;
  int lane = threadIdx.x & 63;
  if (n >= NN) return;
  float dn = dinv[n];
  int jb = off[n], je = off[n + 1];
  float acc = bf2f(H3[(size_t)n * 64 + lane]);
  int j = jb;
  int ja = (jb + 7) & ~7;
  if (ja > je) ja = je;
  for (; j < ja; ++j) acc += bf2f(H3[(size_t)ssrc[j] * 64 + lane]);
  for (; j + 7 < je; j += 8) {
    uint4 sp = *(const uint4*)(ssrc + j);
    unsigned s0 = sp.x & 0xFFFFu, s1 = sp.x >> 16;
    unsigned s2 = sp.y & 0xFFFFu, s3 = sp.y >> 16;
    unsigned s4 = sp.z & 0xFFFFu, s5 = sp.z >> 16;
    unsigned s6 = sp.w & 0xFFFFu, s7 = sp.w >> 16;
    float h0 = bf2f(H3[(size_t)s0 * 64 + lane]);
    float h1 = bf2f(H3[(size_t)s1 * 64 + lane]);
    float h2 = bf2f(H3[(size_t)s2 * 64 + lane]);
    float h3 = bf2f(H3[(size_t)s3 * 64 + lane]);
    float h4 = bf2f(H3[(size_t)s4 * 64 + lane]);
    float h5 = bf2f(H3[(size_t)s5 * 64 + lane]);
    float h6 = bf2f(H3[(size_t)s6 * 64 + lane]);
    float h7 = bf2f(H3[(size_t)s7 * 64 + lane]);
    acc += h0 + h1 + h2 + h3 + h4 + h5 + h6 + h7;
  }
  for (; j < je; ++j) acc += bf2f(H3[(size_t)ssrc[j] * 64 + lane]);
  out[(size_t)n * 64 + lane] = fmaxf(fmaf(dn, acc, b2[lane]), 0.f);
}

extern "C" void kernel_launch(void* const* d_in, const int* in_sizes, int n_in,
                              void* d_out, int out_size, void* d_ws, size_t ws_size,
                              hipStream_t stream) {
  const float* x  = (const float*)d_in[0];
  const int*   ei = (const int*)d_in[1];
  const float* W1 = (const float*)d_in[2];
  const float* b1 = (const float*)d_in[3];
  const float* W2 = (const float*)d_in[4];
  const float* b2 = (const float*)d_in[5];
  const int* esrc = ei;
  const int* edst = ei + NE;

  char* ws = (char*)d_ws;
  unsigned* gcur  = (unsigned*)(ws + 0);
  int*      off   = (int*)(ws + 2048);
  float*    dinv  = (float*)(ws + 204800);
  unsigned short* ssrc = (unsigned short*)(ws + 405504);   // 1.6 MB
  unsigned short* W1T  = (unsigned short*)(ws + 2013184);  // 32 KB
  unsigned short* W2T  = (unsigned short*)(ws + 2045952);  // 16 KB
  unsigned* part  = (unsigned*)(ws + 2097152);             // ~4 MB
  unsigned* Hb    = (unsigned*)(ws + 6291456);             // 12.8 MB
  unsigned* H2    = (unsigned*)(ws + 19922944);            // 12.8 MB
  unsigned short* H3 = (unsigned short*)(ws + 33554432);   // 6.4 MB

  hipLaunchKernelGGL(k_prep, dim3(64), dim3(256), 0, stream, W1, W2, W1T, W2T, gcur);
  hipLaunchKernelGGL(k_partmm1, dim3(NPART + (NN + 63) / 64), dim3(256), 0, stream,
                     esrc, edst, gcur, part, x, W1T, Hb);
  hipLaunchKernelGGL(k_bucket, dim3(NBUCK), dim3(256), 0, stream,
                     gcur, part, off, dinv, ssrc, Hb);
  hipLaunchKernelGGL(k_agg1, dim3((NN + 3) / 4), dim3(256), 0, stream,
                     Hb, off, ssrc, dinv, b1, H2);
  hipLaunchKernelGGL(k_mm2, dim3((NN + 63) / 64), dim3(256), 0, stream,
                     H2, W2T, dinv, (unsigned*)H3);
  hipLaunchKernelGGL(k_agg2, dim3((NN + 3) / 4), dim3(256), 0, stream,
                     H3, off, ssrc, dinv, b2, (float*)d_out);
}